// Round 4
// baseline (541.891 us; speedup 1.0000x reference)
//
#include <hip/hip_runtime.h>
#include <hip/hip_bf16.h>
#include <cstdint>
#include <cstddef>

using u16 = unsigned short;
using u32 = unsigned int;
using u64 = unsigned long long;

typedef __attribute__((ext_vector_type(8))) __bf16 bf16x8;
typedef __attribute__((ext_vector_type(4))) float f32x4;
typedef __attribute__((ext_vector_type(2))) float f32x2;
typedef __attribute__((ext_vector_type(4))) u32 u32x4;

typedef const __attribute__((address_space(1))) void* gas_ptr;
typedef __attribute__((address_space(3))) void* las_ptr;

__device__ __forceinline__ void async_cp16(const void* g, void* l) {
  __builtin_amdgcn_global_load_lds((gas_ptr)g, (las_ptr)l, 16, 0, 0);
}

__device__ __forceinline__ float bf2f(u16 u) {
  u32 v = ((u32)u) << 16;
  return __builtin_bit_cast(float, v);
}
__device__ __forceinline__ u16 f2bf(float f) {
  u32 v = __builtin_bit_cast(u32, f);
  u32 r = (v + 0x7fffu + ((v >> 16) & 1u)) >> 16;  // RNE
  return (u16)r;
}

__device__ __forceinline__ f32x4 mfma16(bf16x8 a, bf16x8 b, f32x4 c) {
  return __builtin_amdgcn_mfma_f32_16x16x32_bf16(a, b, c, 0, 0, 0);
}

// fused convert for x, wq, wk, wv (all independent, pre-QKV-gemm)
__global__ __launch_bounds__(256) void cvt4(const float* __restrict__ x,
                                            const float* __restrict__ wq,
                                            const float* __restrict__ wk,
                                            const float* __restrict__ wv,
                                            u16* __restrict__ xb,
                                            u16* __restrict__ wqkv) {
  const int B0 = 1048576;            // x: 2048*4096/8
  const int B1 = B0 + 2097152;       // wq: 4096*4096/8
  const int B2 = B1 + 524288;        // wk: 1024*4096/8
  const int B3 = B2 + 524288;        // wv
  int i = blockIdx.x * blockDim.x + threadIdx.x;
  int stride = gridDim.x * blockDim.x;
  for (; i < B3; i += stride) {
    const float* src; u16* dst; int j;
    if (i < B0)      { src = x;  dst = xb;                           j = i; }
    else if (i < B1) { src = wq; dst = wqkv;                         j = i - B0; }
    else if (i < B2) { src = wk; dst = wqkv + (size_t)4096 * 4096;   j = i - B1; }
    else             { src = wv; dst = wqkv + (size_t)5120 * 4096;   j = i - B2; }
    const float4* p = (const float4*)(src + (size_t)j * 8);
    float4 a = p[0], b = p[1];
    union { u16 us[8]; u32x4 v; } o;
    o.us[0] = f2bf(a.x); o.us[1] = f2bf(a.y); o.us[2] = f2bf(a.z); o.us[3] = f2bf(a.w);
    o.us[4] = f2bf(b.x); o.us[5] = f2bf(b.y); o.us[6] = f2bf(b.z); o.us[7] = f2bf(b.w);
    *(u32x4*)(dst + (size_t)j * 8) = o.v;
  }
}

// ---------------------------------------------------------------- GEMM C = A * B^T
// MODE 1: C is f32 row-major (out-projection); B is staged DIRECTLY from the
//         f32 source Bf (wo) via reg-stage + in-register bf16 cvt — same LDS
//         bytes/swizzle the async path would produce. Deletes the standalone
//         wo convert pass.
// MODE 2: fused QKV epilogue — per-tile RoPE+RMSNorm for Q/K cols, transposed
//         store for V cols. Each 128-col n-tile is exactly one head (128-dim).
template <int MODE>
__global__ __launch_bounds__(256, 3) void gemm_bt(const u16* __restrict__ A,
                                                  const u16* __restrict__ B,
                                                  const float* __restrict__ Bf,
                                                  void* __restrict__ Cv,
                                                  int M, int N, int K,
                                                  u16* __restrict__ qh,
                                                  u16* __restrict__ khh,
                                                  u16* __restrict__ vt,
                                                  const float* __restrict__ freqs) {
  __shared__ __align__(16) u16 As[128 * 64];
  __shared__ __align__(16) u16 Bs[128 * 64];
  const int tid = threadIdx.x;
  const int wave = tid >> 6, lane = tid & 63;
  const int quad = lane >> 4, c16 = lane & 15;

  const int mb = M >> 7, nb = N >> 7;
  const int per_xcd_n = nb >> 3;
  const int xcd = blockIdx.x & 7, lid = blockIdx.x >> 3;
  const int m_t = lid % mb, n_local = lid / mb;
  const int m0 = m_t * 128, n0 = (xcd * per_xcd_n + n_local) * 128;

  const int wm = (wave & 1) * 64, wn = (wave >> 1) * 64;

  f32x4 acc[4][4] = {};

  const u16* Ab = A + (size_t)m0 * K;

  for (int k0 = 0; k0 < K; k0 += 64) {
    __syncthreads();
#pragma unroll
    for (int i = 0; i < 4; ++i) {
      int idx = tid + 256 * i;
      int row = idx >> 3, sg = (idx & 7) ^ (row & 7);
      async_cp16(Ab + (size_t)row * K + k0 + sg * 8, As + (size_t)idx * 8);
    }
    if constexpr (MODE == 2) {
      const u16* Bb = B + (size_t)n0 * K;
#pragma unroll
      for (int i = 0; i < 4; ++i) {
        int idx = tid + 256 * i;
        int row = idx >> 3, sg = (idx & 7) ^ (row & 7);
        async_cp16(Bb + (size_t)row * K + k0 + sg * 8, Bs + (size_t)idx * 8);
      }
      asm volatile("s_waitcnt vmcnt(0)" ::: "memory");
    } else {
      // reg-stage B from f32 source; identical LDS layout to the async path
      const float* Bbf = Bf + (size_t)n0 * K;
      float4 bv[8];
#pragma unroll
      for (int i = 0; i < 4; ++i) {
        int idx = tid + 256 * i;
        int row = idx >> 3, sg = (idx & 7) ^ (row & 7);
        const float* s = Bbf + (size_t)row * K + k0 + sg * 8;
        bv[2 * i]     = *(const float4*)s;
        bv[2 * i + 1] = *(const float4*)(s + 4);
      }
      asm volatile("s_waitcnt vmcnt(0)" ::: "memory");
#pragma unroll
      for (int i = 0; i < 4; ++i) {
        int idx = tid + 256 * i;
        union { __bf16 h[8]; u32x4 v; } o;
        o.h[0] = (__bf16)bv[2 * i].x;     o.h[1] = (__bf16)bv[2 * i].y;
        o.h[2] = (__bf16)bv[2 * i].z;     o.h[3] = (__bf16)bv[2 * i].w;
        o.h[4] = (__bf16)bv[2 * i + 1].x; o.h[5] = (__bf16)bv[2 * i + 1].y;
        o.h[6] = (__bf16)bv[2 * i + 1].z; o.h[7] = (__bf16)bv[2 * i + 1].w;
        *(u32x4*)(Bs + (size_t)idx * 8) = o.v;
      }
    }
    __syncthreads();

    bf16x8 af[4][2], bfr[4][2];
#pragma unroll
    for (int mt = 0; mt < 4; ++mt) {
      int row = wm + mt * 16 + c16;
#pragma unroll
      for (int c = 0; c < 2; ++c)
        af[mt][c] = *(const bf16x8*)(As + row * 64 + (((c * 4 + quad) ^ (row & 7)) * 8));
    }
#pragma unroll
    for (int nt = 0; nt < 4; ++nt) {
      int row = wn + nt * 16 + c16;
#pragma unroll
      for (int c = 0; c < 2; ++c)
        bfr[nt][c] = *(const bf16x8*)(Bs + row * 64 + (((c * 4 + quad) ^ (row & 7)) * 8));
    }
#pragma unroll
    for (int c = 0; c < 2; ++c)
#pragma unroll
      for (int mt = 0; mt < 4; ++mt)
#pragma unroll
        for (int nt = 0; nt < 4; ++nt)
          acc[mt][nt] = mfma16(af[mt][c], bfr[nt][c], acc[mt][nt]);
  }

  if constexpr (MODE == 1) {
#pragma unroll
    for (int mt = 0; mt < 4; ++mt) {
#pragma unroll
      for (int nt = 0; nt < 4; ++nt) {
#pragma unroll
        for (int r = 0; r < 4; ++r) {
          int gm = m0 + wm + mt * 16 + quad * 4 + r;
          int gn = n0 + wn + nt * 16 + c16;
          ((float*)Cv)[(size_t)gm * N + gn] = acc[mt][nt][r];
        }
      }
    }
  } else {
    // ------- fused QKV epilogue -------
    __syncthreads();  // all waves done reading As/Bs; reuse As as f32 scratch
    float* sums = (float*)As;
    if (n0 < 5120) {
      // ---- Q or K head: RoPE (pairs = adjacent lanes), then RMSNorm over 128
      float ss_arr[4][4];
#pragma unroll
      for (int mt = 0; mt < 4; ++mt) {
#pragma unroll
        for (int r = 0; r < 4; ++r) {
          int s = m0 + wm + mt * 16 + quad * 4 + r;
          const float* fb = freqs + (size_t)s * 128;
          float ssv = 0.0f;
#pragma unroll
          for (int nt = 0; nt < 4; ++nt) {
            int d = wn + nt * 16 + c16;
            float v = acc[mt][nt][r];
            float p = __shfl_xor(v, 1, 64);         // partner of the (even,odd) pair
            f32x2 ff = *(const f32x2*)(fb + (d & ~1));  // (cos, sin)
            float res = (c16 & 1) ? fmaf(v, ff.x, p * ff.y)
                                  : fmaf(v, ff.x, -p * ff.y);
            acc[mt][nt][r] = res;
            ssv = fmaf(res, res, ssv);
          }
#pragma unroll
          for (int m = 1; m < 16; m <<= 1) ssv += __shfl_xor(ssv, m, 64);
          ss_arr[mt][r] = ssv;
        }
      }
      const int wn_idx = wave >> 1;
      if (c16 == 0) {
#pragma unroll
        for (int mt = 0; mt < 4; ++mt)
#pragma unroll
          for (int r = 0; r < 4; ++r)
            sums[wn_idx * 128 + wm + mt * 16 + quad * 4 + r] = ss_arr[mt][r];
      }
      __syncthreads();
      u16* outb = (n0 < 4096)
                      ? (qh + (size_t)(n0 >> 7) * M * 128)
                      : (khh + (size_t)((n0 - 4096) >> 7) * M * 128);
#pragma unroll
      for (int mt = 0; mt < 4; ++mt) {
#pragma unroll
        for (int r = 0; r < 4; ++r) {
          int rl = wm + mt * 16 + quad * 4 + r;
          float tot = ss_arr[mt][r] + sums[(wn_idx ^ 1) * 128 + rl];
          float scl = rsqrtf(tot * (1.0f / 128.0f) + 1e-5f);
          int s = m0 + rl;
#pragma unroll
          for (int nt = 0; nt < 4; ++nt)
            outb[(size_t)s * 128 + wn + nt * 16 + c16] = f2bf(acc[mt][nt][r] * scl);
        }
      }
    } else {
      // ---- V head: store transposed vt[dv][s], 4 consecutive s packed per store
#pragma unroll
      for (int mt = 0; mt < 4; ++mt) {
#pragma unroll
        for (int nt = 0; nt < 4; ++nt) {
          int dv = (n0 - 5120) + wn + nt * 16 + c16;
          int s0 = m0 + wm + mt * 16 + quad * 4;
          union { u16 us[4]; u64 v; } pk;
#pragma unroll
          for (int r = 0; r < 4; ++r) pk.us[r] = f2bf(acc[mt][nt][r]);
          *(u64*)(vt + (size_t)dv * M + s0) = pk.v;
        }
      }
    }
  }
}

// ---------------------------------------------------------------- flash attention
// (reverted to the round-1/2 version — the 459.6 µs anchor)
// 256 blocks x 512 threads. Waves 0-3 far q-tile (15-p), waves 4-7 near tile
// (p), concurrent, sharing one K/V staging stream.
#define SEQ 2048
__global__ __launch_bounds__(512, 2) void attn(const u16* __restrict__ Q,
                                               const u16* __restrict__ Kh,
                                               const u16* __restrict__ VT,
                                               u16* __restrict__ O) {
  __shared__ __align__(16) u16 Ks[2][64 * 128];
  __shared__ __align__(16) u16 Vs[2][128 * 64];
  __shared__ __align__(16) u16 Ps[8][32 * 64];
  const int tid = threadIdx.x;
  const int wave = tid >> 6, lane = tid & 63;
  const int quad = lane >> 4, c16 = lane & 15;
  const int bid = blockIdx.x;
  const int hk = bid & 7;        // kv-head pinned to one XCD's L2
  const int rest = bid >> 3;
  const int hq = rest & 3;
  const int p = rest >> 2;       // 0..7
  const int h = hk * 4 + hq;

  const int wl = wave & 3, grp = wave >> 2;
  const int qt = grp ? p : (15 - p);        // grp0 = far tile, grp1 = near tile
  const int q0w = qt * 128 + wl * 32;
  const int kend = (15 - p) * 128 + 128;    // block-uniform (covers far tile)

  const float sc = 0.12751743f;  // log2(e)/sqrt(128)
  const float B = 16.5f;
  const u16* Kb = Kh + (size_t)hk * SEQ * 128;
  const u16* Vb = VT + (size_t)hk * 128 * SEQ;

  auto stage = [&](int t0, int b) __attribute__((always_inline)) {
#pragma unroll
    for (int i = 0; i < 2; ++i) {
      int idx = tid + 512 * i;
      int row = idx >> 4, sg = (idx & 15) ^ (row & 7);
      async_cp16(Kb + (size_t)(t0 + row) * 128 + sg * 8, &Ks[b][(size_t)idx * 8]);
    }
#pragma unroll
    for (int i = 0; i < 2; ++i) {
      int idx = tid + 512 * i;
      int row = idx >> 3, sg = (idx & 7) ^ (row & 7);
      async_cp16(Vb + (size_t)row * SEQ + t0 + sg * 8, &Vs[b][(size_t)idx * 8]);
    }
  };

  bf16x8 qfr[2][4];
  const u16* qbase = Q + (size_t)h * SEQ * 128;
#pragma unroll
  for (int g = 0; g < 2; ++g)
#pragma unroll
    for (int c = 0; c < 4; ++c)
      qfr[g][c] =
          *(const bf16x8*)(qbase + (size_t)(q0w + g * 16 + c16) * 128 + c * 32 + quad * 8);

  f32x4 o_acc[2][8] = {};
  float lsum[2][4] = {};

  stage(0, 0);

#pragma unroll 1
  for (int t0 = 0; t0 < kend; t0 += 64) {
    const int cur = (t0 >> 6) & 1;
    asm volatile("s_waitcnt vmcnt(0)" ::: "memory");
    __syncthreads();
    if (t0 + 64 < kend) stage(t0 + 64, cur ^ 1);

    if (t0 < q0w + 32) {
      f32x4 sa[2][4] = {};
      __builtin_amdgcn_s_setprio(1);
#pragma unroll
      for (int ct = 0; ct < 4; ++ct) {
        int t = ct * 16 + c16;
        int tbase = t * 128;
        int tsw = t & 7;
#pragma unroll
        for (int c = 0; c < 4; ++c) {
          bf16x8 kf = *(const bf16x8*)(&Ks[cur][tbase + (((c * 4 + quad) ^ tsw) * 8)]);
          sa[0][ct] = mfma16(qfr[0][c], kf, sa[0][ct]);
          sa[1][ct] = mfma16(qfr[1][c], kf, sa[1][ct]);
        }
      }
      __builtin_amdgcn_s_setprio(0);

      const bool diag = (t0 + 64 > q0w);
      auto soft = [&](bool masked) __attribute__((always_inline)) {
#pragma unroll
        for (int g = 0; g < 2; ++g) {
#pragma unroll
          for (int r = 0; r < 4; ++r) {
            int row = g * 16 + quad * 4 + r;
            int row_q = q0w + row;
            int rbase = row * 64;
            int rsw = row & 7;
#pragma unroll
            for (int ct = 0; ct < 4; ++ct) {
              float s = sa[g][ct][r];
              float arg = fmaf(s, sc, -B);
              if (masked) {
                int t_idx = t0 + ct * 16 + c16;
                arg = (t_idx <= row_q) ? arg : -1.0e30f;
              }
              float pe = exp2f(arg);
              lsum[g][r] += pe;
              u32 pb = (__builtin_bit_cast(u32, pe) + 0x8000u) >> 16;
              Ps[wave][rbase + (((ct * 2 + (c16 >> 3)) ^ rsw) * 8) + (c16 & 7)] = (u16)pb;
            }
          }
        }
      };
      if (diag) soft(true); else soft(false);
      asm volatile("s_waitcnt lgkmcnt(0)" ::: "memory");

      __builtin_amdgcn_s_setprio(1);
#pragma unroll
      for (int tc = 0; tc < 2; ++tc) {
        bf16x8 pf[2];
#pragma unroll
        for (int g = 0; g < 2; ++g) {
          int prow = g * 16 + c16;
          pf[g] = *(const bf16x8*)(&Ps[wave][prow * 64 + (((tc * 4 + quad) ^ (prow & 7)) * 8)]);
        }
#pragma unroll
        for (int nt = 0; nt < 8; ++nt) {
          int dl = nt * 16 + c16;
          bf16x8 vf = *(const bf16x8*)(&Vs[cur][dl * 64 + (((tc * 4 + quad) ^ (dl & 7)) * 8)]);
          o_acc[0][nt] = mfma16(pf[0], vf, o_acc[0][nt]);
          o_acc[1][nt] = mfma16(pf[1], vf, o_acc[1][nt]);
        }
      }
      __builtin_amdgcn_s_setprio(0);
    }
  }

#pragma unroll
  for (int g = 0; g < 2; ++g) {
#pragma unroll
    for (int r = 0; r < 4; ++r) {
      float l = lsum[g][r];
#pragma unroll
      for (int m = 1; m < 16; m <<= 1) l += __shfl_xor(l, m, 64);
      float inv = 1.0f / l;
      int s_idx = q0w + g * 16 + quad * 4 + r;
      u16* ob = O + (size_t)s_idx * 4096 + (size_t)h * 128;
#pragma unroll
      for (int nt = 0; nt < 8; ++nt) ob[nt * 16 + c16] = f2bf(o_acc[g][nt][r] * inv);
    }
  }
}

// ---------------------------------------------------------------- launch
extern "C" void kernel_launch(void* const* d_in, const int* in_sizes, int n_in,
                              void* d_out, int out_size, void* d_ws, size_t ws_size,
                              hipStream_t stream) {
  const float* x  = (const float*)d_in[0];
  const float* wq = (const float*)d_in[1];
  const float* wk = (const float*)d_in[2];
  const float* wv = (const float*)d_in[3];
  const float* wo = (const float*)d_in[4];
  const float* fr = (const float*)d_in[5];
  float* out = (float*)d_out;

  const size_t S = 2048, D = 4096, KV = 1024, NQKV = D + 2 * KV;  // 6144
  u16* p = (u16*)d_ws;
  u16* xb   = p; p += S * D;
  u16* wqkv = p; p += NQKV * D;
  u16* qh   = p; p += S * D;
  u16* khh  = p; p += S * KV;
  u16* vt   = p; p += KV * S;
  u16* ob   = p; p += S * D;

  // fused convert of x, wq, wk, wv (one launch)
  cvt4<<<dim3(2048), dim3(256), 0, stream>>>(x, wq, wk, wv, xb, wqkv);

  // fused QKV GEMM + RoPE/RMSNorm/V-transpose epilogue (writes qh/khh/vt directly)
  gemm_bt<2><<<dim3((S / 128) * (NQKV / 128)), dim3(256), 0, stream>>>(
      xb, wqkv, nullptr, nullptr, (int)S, (int)NQKV, (int)D, qh, khh, vt, fr);

  attn<<<dim3(256), dim3(512), 0, stream>>>(qh, khh, vt, ob);

  // out-projection: B staged directly from f32 wo (no separate convert pass)
  gemm_bt<1><<<dim3((S / 128) * (D / 128)), dim3(256), 0, stream>>>(
      ob, nullptr, wo, (void*)out, (int)S, (int)D, (int)D,
      nullptr, nullptr, nullptr, nullptr);
}

// Round 5
// 454.868 us; speedup vs baseline: 1.1913x; 1.1913x over previous
//
#include <hip/hip_runtime.h>
#include <hip/hip_bf16.h>
#include <cstdint>
#include <cstddef>

using u16 = unsigned short;
using u32 = unsigned int;
using u64 = unsigned long long;

typedef __attribute__((ext_vector_type(8))) __bf16 bf16x8;
typedef __attribute__((ext_vector_type(4))) float f32x4;
typedef __attribute__((ext_vector_type(2))) float f32x2;
typedef __attribute__((ext_vector_type(4))) u32 u32x4;

typedef const __attribute__((address_space(1))) void* gas_ptr;
typedef __attribute__((address_space(3))) void* las_ptr;

__device__ __forceinline__ void async_cp16(const void* g, void* l) {
  __builtin_amdgcn_global_load_lds((gas_ptr)g, (las_ptr)l, 16, 0, 0);
}

__device__ __forceinline__ float bf2f(u16 u) {
  u32 v = ((u32)u) << 16;
  return __builtin_bit_cast(float, v);
}
__device__ __forceinline__ u16 f2bf(float f) {
  u32 v = __builtin_bit_cast(u32, f);
  u32 r = (v + 0x7fffu + ((v >> 16) & 1u)) >> 16;  // RNE
  return (u16)r;
}

__device__ __forceinline__ f32x4 mfma16(bf16x8 a, bf16x8 b, f32x4 c) {
  return __builtin_amdgcn_mfma_f32_16x16x32_bf16(a, b, c, 0, 0, 0);
}

// fused convert for x, wq, wk, wv (all independent, pre-QKV-gemm)
__global__ __launch_bounds__(256) void cvt4(const float* __restrict__ x,
                                            const float* __restrict__ wq,
                                            const float* __restrict__ wk,
                                            const float* __restrict__ wv,
                                            u16* __restrict__ xb,
                                            u16* __restrict__ wqkv) {
  const int B0 = 1048576;            // x: 2048*4096/8
  const int B1 = B0 + 2097152;       // wq: 4096*4096/8
  const int B2 = B1 + 524288;        // wk: 1024*4096/8
  const int B3 = B2 + 524288;        // wv
  int i = blockIdx.x * blockDim.x + threadIdx.x;
  int stride = gridDim.x * blockDim.x;
  for (; i < B3; i += stride) {
    const float* src; u16* dst; int j;
    if (i < B0)      { src = x;  dst = xb;                           j = i; }
    else if (i < B1) { src = wq; dst = wqkv;                         j = i - B0; }
    else if (i < B2) { src = wk; dst = wqkv + (size_t)4096 * 4096;   j = i - B1; }
    else             { src = wv; dst = wqkv + (size_t)5120 * 4096;   j = i - B2; }
    const float4* p = (const float4*)(src + (size_t)j * 8);
    float4 a = p[0], b = p[1];
    union { u16 us[8]; u32x4 v; } o;
    o.us[0] = f2bf(a.x); o.us[1] = f2bf(a.y); o.us[2] = f2bf(a.z); o.us[3] = f2bf(a.w);
    o.us[4] = f2bf(b.x); o.us[5] = f2bf(b.y); o.us[6] = f2bf(b.z); o.us[7] = f2bf(b.w);
    *(u32x4*)(dst + (size_t)j * 8) = o.v;
  }
}

// ---------------------------------------------------------------- GEMM C = A * B^T
// MODE 1: C is f32 row-major (out-projection). B async-staged bf16 (R4's f32
//         reg-stage reverted: it thrashed L2 and exposed HBM latency, 90->190us).
// MODE 2: fused QKV epilogue — per-tile RoPE+RMSNorm for Q/K cols, transposed
//         store for V cols. Each 128-col n-tile is exactly one head (128-dim).
template <int MODE>
__global__ __launch_bounds__(256, 3) void gemm_bt(const u16* __restrict__ A,
                                                  const u16* __restrict__ B,
                                                  void* __restrict__ Cv,
                                                  int M, int N, int K,
                                                  u16* __restrict__ qh,
                                                  u16* __restrict__ khh,
                                                  u16* __restrict__ vt,
                                                  const float* __restrict__ freqs) {
  __shared__ __align__(16) u16 As[128 * 64];
  __shared__ __align__(16) u16 Bs[128 * 64];
  const int tid = threadIdx.x;
  const int wave = tid >> 6, lane = tid & 63;
  const int quad = lane >> 4, c16 = lane & 15;

  const int mb = M >> 7, nb = N >> 7;
  const int per_xcd_n = nb >> 3;
  const int xcd = blockIdx.x & 7, lid = blockIdx.x >> 3;
  const int m_t = lid % mb, n_local = lid / mb;
  const int m0 = m_t * 128, n0 = (xcd * per_xcd_n + n_local) * 128;

  const int wm = (wave & 1) * 64, wn = (wave >> 1) * 64;

  f32x4 acc[4][4] = {};

  const u16* Ab = A + (size_t)m0 * K;
  const u16* Bb = B + (size_t)n0 * K;

  for (int k0 = 0; k0 < K; k0 += 64) {
    __syncthreads();
#pragma unroll
    for (int i = 0; i < 4; ++i) {
      int idx = tid + 256 * i;
      int row = idx >> 3, sg = (idx & 7) ^ (row & 7);
      async_cp16(Ab + (size_t)row * K + k0 + sg * 8, As + (size_t)idx * 8);
    }
#pragma unroll
    for (int i = 0; i < 4; ++i) {
      int idx = tid + 256 * i;
      int row = idx >> 3, sg = (idx & 7) ^ (row & 7);
      async_cp16(Bb + (size_t)row * K + k0 + sg * 8, Bs + (size_t)idx * 8);
    }
    asm volatile("s_waitcnt vmcnt(0)" ::: "memory");
    __syncthreads();

    bf16x8 af[4][2], bfr[4][2];
#pragma unroll
    for (int mt = 0; mt < 4; ++mt) {
      int row = wm + mt * 16 + c16;
#pragma unroll
      for (int c = 0; c < 2; ++c)
        af[mt][c] = *(const bf16x8*)(As + row * 64 + (((c * 4 + quad) ^ (row & 7)) * 8));
    }
#pragma unroll
    for (int nt = 0; nt < 4; ++nt) {
      int row = wn + nt * 16 + c16;
#pragma unroll
      for (int c = 0; c < 2; ++c)
        bfr[nt][c] = *(const bf16x8*)(Bs + row * 64 + (((c * 4 + quad) ^ (row & 7)) * 8));
    }
#pragma unroll
    for (int c = 0; c < 2; ++c)
#pragma unroll
      for (int mt = 0; mt < 4; ++mt)
#pragma unroll
        for (int nt = 0; nt < 4; ++nt)
          acc[mt][nt] = mfma16(af[mt][c], bfr[nt][c], acc[mt][nt]);
  }

  if constexpr (MODE == 1) {
#pragma unroll
    for (int mt = 0; mt < 4; ++mt) {
#pragma unroll
      for (int nt = 0; nt < 4; ++nt) {
#pragma unroll
        for (int r = 0; r < 4; ++r) {
          int gm = m0 + wm + mt * 16 + quad * 4 + r;
          int gn = n0 + wn + nt * 16 + c16;
          ((float*)Cv)[(size_t)gm * N + gn] = acc[mt][nt][r];
        }
      }
    }
  } else {
    // ------- fused QKV epilogue -------
    __syncthreads();  // all waves done reading As/Bs; reuse As as f32 scratch
    float* sums = (float*)As;
    if (n0 < 5120) {
      // ---- Q or K head: RoPE (pairs = adjacent lanes), then RMSNorm over 128
      float ss_arr[4][4];
#pragma unroll
      for (int mt = 0; mt < 4; ++mt) {
#pragma unroll
        for (int r = 0; r < 4; ++r) {
          int s = m0 + wm + mt * 16 + quad * 4 + r;
          const float* fb = freqs + (size_t)s * 128;
          float ssv = 0.0f;
#pragma unroll
          for (int nt = 0; nt < 4; ++nt) {
            int d = wn + nt * 16 + c16;
            float v = acc[mt][nt][r];
            float p = __shfl_xor(v, 1, 64);         // partner of the (even,odd) pair
            f32x2 ff = *(const f32x2*)(fb + (d & ~1));  // (cos, sin)
            float res = (c16 & 1) ? fmaf(v, ff.x, p * ff.y)
                                  : fmaf(v, ff.x, -p * ff.y);
            acc[mt][nt][r] = res;
            ssv = fmaf(res, res, ssv);
          }
#pragma unroll
          for (int m = 1; m < 16; m <<= 1) ssv += __shfl_xor(ssv, m, 64);
          ss_arr[mt][r] = ssv;
        }
      }
      const int wn_idx = wave >> 1;
      if (c16 == 0) {
#pragma unroll
        for (int mt = 0; mt < 4; ++mt)
#pragma unroll
          for (int r = 0; r < 4; ++r)
            sums[wn_idx * 128 + wm + mt * 16 + quad * 4 + r] = ss_arr[mt][r];
      }
      __syncthreads();
      u16* outb = (n0 < 4096)
                      ? (qh + (size_t)(n0 >> 7) * M * 128)
                      : (khh + (size_t)((n0 - 4096) >> 7) * M * 128);
#pragma unroll
      for (int mt = 0; mt < 4; ++mt) {
#pragma unroll
        for (int r = 0; r < 4; ++r) {
          int rl = wm + mt * 16 + quad * 4 + r;
          float tot = ss_arr[mt][r] + sums[(wn_idx ^ 1) * 128 + rl];
          float scl = rsqrtf(tot * (1.0f / 128.0f) + 1e-5f);
          int s = m0 + rl;
#pragma unroll
          for (int nt = 0; nt < 4; ++nt)
            outb[(size_t)s * 128 + wn + nt * 16 + c16] = f2bf(acc[mt][nt][r] * scl);
        }
      }
    } else {
      // ---- V head: store transposed vt[dv][s], 4 consecutive s packed per store
#pragma unroll
      for (int mt = 0; mt < 4; ++mt) {
#pragma unroll
        for (int nt = 0; nt < 4; ++nt) {
          int dv = (n0 - 5120) + wn + nt * 16 + c16;
          int s0 = m0 + wm + mt * 16 + quad * 4;
          union { u16 us[4]; u64 v; } pk;
#pragma unroll
          for (int r = 0; r < 4; ++r) pk.us[r] = f2bf(acc[mt][nt][r]);
          *(u64*)(vt + (size_t)dv * M + s0) = pk.v;
        }
      }
    }
  }
}

// ---------------------------------------------------------------- flash attention
// R2 anchor version (256 blocks x 512 threads, split wave-groups on tile pair
// {15-p, p}) + NEW: wo->bf16 conversion stuffed into the per-block idle slack.
// Blocks with small kend (large p) finish early and the whole grid is 1
// block/CU, so late-finishing CUs gate the next kernel; the cvt slice is
// sized proportional to p (p=0 critical blocks do zero), hiding the former
// 18us serial cvt_wo pass inside attn's makespan.
#define SEQ 2048
__global__ __launch_bounds__(512, 2) void attn(const u16* __restrict__ Q,
                                               const u16* __restrict__ Kh,
                                               const u16* __restrict__ VT,
                                               u16* __restrict__ O,
                                               const float* __restrict__ wo,
                                               u16* __restrict__ wob) {
  __shared__ __align__(16) u16 Ks[2][64 * 128];
  __shared__ __align__(16) u16 Vs[2][128 * 64];
  __shared__ __align__(16) u16 Ps[8][32 * 64];
  const int tid = threadIdx.x;
  const int wave = tid >> 6, lane = tid & 63;
  const int quad = lane >> 4, c16 = lane & 15;
  const int bid = blockIdx.x;
  const int hk = bid & 7;        // kv-head pinned to one XCD's L2
  const int rest = bid >> 3;
  const int hq = rest & 3;
  const int p = rest >> 2;       // 0..7
  const int h = hk * 4 + hq;

  const int wl = wave & 3, grp = wave >> 2;
  const int qt = grp ? p : (15 - p);        // grp0 = far tile, grp1 = near tile
  const int q0w = qt * 128 + wl * 32;
  const int kend = (15 - p) * 128 + 128;    // block-uniform (covers far tile)

  const float sc = 0.12751743f;  // log2(e)/sqrt(128)
  const float B = 16.5f;
  const u16* Kb = Kh + (size_t)hk * SEQ * 128;
  const u16* Vb = VT + (size_t)hk * 128 * SEQ;

  auto stage = [&](int t0, int b) __attribute__((always_inline)) {
#pragma unroll
    for (int i = 0; i < 2; ++i) {
      int idx = tid + 512 * i;
      int row = idx >> 4, sg = (idx & 15) ^ (row & 7);
      async_cp16(Kb + (size_t)(t0 + row) * 128 + sg * 8, &Ks[b][(size_t)idx * 8]);
    }
#pragma unroll
    for (int i = 0; i < 2; ++i) {
      int idx = tid + 512 * i;
      int row = idx >> 3, sg = (idx & 7) ^ (row & 7);
      async_cp16(Vb + (size_t)row * SEQ + t0 + sg * 8, &Vs[b][(size_t)idx * 8]);
    }
  };

  bf16x8 qfr[2][4];
  const u16* qbase = Q + (size_t)h * SEQ * 128;
#pragma unroll
  for (int g = 0; g < 2; ++g)
#pragma unroll
    for (int c = 0; c < 4; ++c)
      qfr[g][c] =
          *(const bf16x8*)(qbase + (size_t)(q0w + g * 16 + c16) * 128 + c * 32 + quad * 8);

  f32x4 o_acc[2][8] = {};
  float lsum[2][4] = {};

  stage(0, 0);

#pragma unroll 1
  for (int t0 = 0; t0 < kend; t0 += 64) {
    const int cur = (t0 >> 6) & 1;
    asm volatile("s_waitcnt vmcnt(0)" ::: "memory");
    __syncthreads();
    if (t0 + 64 < kend) stage(t0 + 64, cur ^ 1);

    if (t0 < q0w + 32) {
      f32x4 sa[2][4] = {};
      __builtin_amdgcn_s_setprio(1);
#pragma unroll
      for (int ct = 0; ct < 4; ++ct) {
        int t = ct * 16 + c16;
        int tbase = t * 128;
        int tsw = t & 7;
#pragma unroll
        for (int c = 0; c < 4; ++c) {
          bf16x8 kf = *(const bf16x8*)(&Ks[cur][tbase + (((c * 4 + quad) ^ tsw) * 8)]);
          sa[0][ct] = mfma16(qfr[0][c], kf, sa[0][ct]);
          sa[1][ct] = mfma16(qfr[1][c], kf, sa[1][ct]);
        }
      }
      __builtin_amdgcn_s_setprio(0);

      const bool diag = (t0 + 64 > q0w);
      auto soft = [&](bool masked) __attribute__((always_inline)) {
#pragma unroll
        for (int g = 0; g < 2; ++g) {
#pragma unroll
          for (int r = 0; r < 4; ++r) {
            int row = g * 16 + quad * 4 + r;
            int row_q = q0w + row;
            int rbase = row * 64;
            int rsw = row & 7;
#pragma unroll
            for (int ct = 0; ct < 4; ++ct) {
              float s = sa[g][ct][r];
              float arg = fmaf(s, sc, -B);
              if (masked) {
                int t_idx = t0 + ct * 16 + c16;
                arg = (t_idx <= row_q) ? arg : -1.0e30f;
              }
              float pe = exp2f(arg);
              lsum[g][r] += pe;
              u32 pb = (__builtin_bit_cast(u32, pe) + 0x8000u) >> 16;
              Ps[wave][rbase + (((ct * 2 + (c16 >> 3)) ^ rsw) * 8) + (c16 & 7)] = (u16)pb;
            }
          }
        }
      };
      if (diag) soft(true); else soft(false);
      asm volatile("s_waitcnt lgkmcnt(0)" ::: "memory");

      __builtin_amdgcn_s_setprio(1);
#pragma unroll
      for (int tc = 0; tc < 2; ++tc) {
        bf16x8 pf[2];
#pragma unroll
        for (int g = 0; g < 2; ++g) {
          int prow = g * 16 + c16;
          pf[g] = *(const bf16x8*)(&Ps[wave][prow * 64 + (((tc * 4 + quad) ^ (prow & 7)) * 8)]);
        }
#pragma unroll
        for (int nt = 0; nt < 8; ++nt) {
          int dl = nt * 16 + c16;
          bf16x8 vf = *(const bf16x8*)(&Vs[cur][dl * 64 + (((tc * 4 + quad) ^ (dl & 7)) * 8)]);
          o_acc[0][nt] = mfma16(pf[0], vf, o_acc[0][nt]);
          o_acc[1][nt] = mfma16(pf[1], vf, o_acc[1][nt]);
        }
      }
      __builtin_amdgcn_s_setprio(0);
    }
  }

#pragma unroll
  for (int g = 0; g < 2; ++g) {
#pragma unroll
    for (int r = 0; r < 4; ++r) {
      float l = lsum[g][r];
#pragma unroll
      for (int m = 1; m < 16; m <<= 1) l += __shfl_xor(l, m, 64);
      float inv = 1.0f / l;
      int s_idx = q0w + g * 16 + quad * 4 + r;
      u16* ob = O + (size_t)s_idx * 4096 + (size_t)h * 128;
#pragma unroll
      for (int nt = 0; nt < 8; ++nt) ob[nt * 16 + c16] = f2bf(o_acc[g][nt][r] * inv);
    }
  }

  // ---- wo->bf16 conversion tail, weighted by p (slack-proportional) ----
  // 896 units total (32 blocks per p, unit weight = p); UNIT chunks each.
  {
    const int UNIT = 2341;                       // 896*2341 >= 2097152
    const int N8 = 2097152;                      // 4096*4096/8
    int su = 16 * p * (p - 1) + (bid & 31) * p;  // prefix units
    int i = su * UNIT + tid;
    int end = su * UNIT + p * UNIT;
    if (end > N8) end = N8;
    for (; i < end; i += 512) {
      const float4* src = (const float4*)(wo + (size_t)i * 8);
      float4 a = src[0], b = src[1];
      union { u16 us[8]; u32x4 v; } o;
      o.us[0] = f2bf(a.x); o.us[1] = f2bf(a.y); o.us[2] = f2bf(a.z); o.us[3] = f2bf(a.w);
      o.us[4] = f2bf(b.x); o.us[5] = f2bf(b.y); o.us[6] = f2bf(b.z); o.us[7] = f2bf(b.w);
      *(u32x4*)(wob + (size_t)i * 8) = o.v;
    }
  }
}

// ---------------------------------------------------------------- launch
extern "C" void kernel_launch(void* const* d_in, const int* in_sizes, int n_in,
                              void* d_out, int out_size, void* d_ws, size_t ws_size,
                              hipStream_t stream) {
  const float* x  = (const float*)d_in[0];
  const float* wq = (const float*)d_in[1];
  const float* wk = (const float*)d_in[2];
  const float* wv = (const float*)d_in[3];
  const float* wo = (const float*)d_in[4];
  const float* fr = (const float*)d_in[5];
  float* out = (float*)d_out;

  const size_t S = 2048, D = 4096, KV = 1024, NQKV = D + 2 * KV;  // 6144
  u16* p = (u16*)d_ws;
  u16* xb   = p; p += S * D;
  u16* wqkv = p; p += NQKV * D;
  u16* qh   = p; p += S * D;
  u16* khh  = p; p += S * KV;
  u16* vt   = p; p += KV * S;
  u16* ob   = p; p += S * D;
  u16* wob = wqkv;  // wqkv dead after QKV gemm; attn writes it, out-proj reads it

  // fused convert of x, wq, wk, wv (one launch)
  cvt4<<<dim3(2048), dim3(256), 0, stream>>>(x, wq, wk, wv, xb, wqkv);

  // fused QKV GEMM + RoPE/RMSNorm/V-transpose epilogue (writes qh/khh/vt directly)
  gemm_bt<2><<<dim3((S / 128) * (NQKV / 128)), dim3(256), 0, stream>>>(
      xb, wqkv, nullptr, (int)S, (int)NQKV, (int)D, qh, khh, vt, fr);

  // attention + slack-scheduled wo conversion
  attn<<<dim3(256), dim3(512), 0, stream>>>(qh, khh, vt, ob, wo, wob);

  gemm_bt<1><<<dim3((S / 128) * (D / 128)), dim3(256), 0, stream>>>(
      ob, wob, (void*)out, (int)S, (int)D, (int)D,
      nullptr, nullptr, nullptr, nullptr);
}